// Round 3
// baseline (3449.435 us; speedup 1.0000x reference)
//
#include <hip/hip_runtime.h>
#include <stdint.h>

#define NE 195480
#define NM 10242
#define NG 65160
#define DD 512
#define NOUT 471

typedef __attribute__((ext_vector_type(8))) short bf16x8;
typedef __attribute__((ext_vector_type(4))) float f32x4;
typedef __attribute__((ext_vector_type(8))) unsigned short ushort8;
typedef __attribute__((ext_vector_type(4))) unsigned short ushort4v;

__device__ __forceinline__ float bf2f(unsigned short u) {
    union { unsigned int i; float f; } v; v.i = ((unsigned int)u) << 16; return v.f;
}
__device__ __forceinline__ unsigned short f2bf(float f) {
    union { float f; unsigned int u; } v; v.f = f;
    unsigned int x = v.u;
    return (unsigned short)((x + 0x7fffu + ((x >> 16) & 1u)) >> 16);
}
__device__ __forceinline__ float silu_f(float x) { return x / (1.f + __expf(-x)); }

__device__ __forceinline__ ushort8 cvt8(const float* __restrict__ p) {
    const f32x4 lo = *(const f32x4*)p;
    const f32x4 hi = *(const f32x4*)(p + 4);
    ushort8 r;
    #pragma unroll
    for (int j = 0; j < 4; ++j) { r[j] = f2bf(lo[j]); r[j + 4] = f2bf(hi[j]); }
    return r;
}

enum { A_PLAIN = 0, A_EDGE = 1, A_NODE = 2 };
enum { E_BIAS_BF16 = 0, E_SILU_BF16 = 1, E_SCATTER = 2, E_RESID_BF16 = 3, E_OUT_F32 = 4 };

// C = epilogue(A @ B + bias). A sources: bf16 workspace (A_PLAIN) or fp32
// gathers (A_EDGE / A_NODE). B/bias: fp32 weights, converted to bf16 at
// staging. 64x64 tile per 256-thread block, 4 waves; wave w owns cols
// [w*16, w*16+16), 4 row-tiles of 16. MFMA 16x16x32 bf16, fp32 accum.
template<int AMODE, int EPI>
__global__ __launch_bounds__(256)
void gemm64(const unsigned short* __restrict__ A,
            const float* __restrict__ B,
            const float* __restrict__ bias,
            int M, int N, int K,
            const float* __restrict__ mesh,
            const float* __restrict__ gridf,
            const unsigned short* __restrict__ e0,
            const int* __restrict__ esrc,
            const int* __restrict__ edst,
            const float* __restrict__ aggIn,
            float* __restrict__ aggOut,
            unsigned short* __restrict__ outB,
            float* __restrict__ outF)
{
    __shared__ unsigned short As[64 * 40];
    __shared__ unsigned short Bs[32 * 68];

    const int tid  = threadIdx.x;
    const int bm   = blockIdx.x, bn = blockIdx.y;
    const int w    = tid >> 6;
    const int lane = tid & 63;
    const int quad = lane >> 4;
    const int ln   = lane & 15;

    // staging roles
    const int ar  = tid >> 2;        // 0..63 : A row within tile
    const int akc = (tid & 3) * 8;   // 0,8,16,24 : A k-chunk
    const int bkr = tid >> 3;        // 0..31 : B k-row
    const int bnc = (tid & 7) * 8;   // 0..56 : B n-chunk

    const int arow_g = bm * 64 + ar;
    const bool arow_ok = (arow_g < M);
    const bool nvec = ((N & 7) == 0);

    f32x4 acc[4] = {};

    for (int k0 = 0; k0 < K; k0 += 32) {
        // ---- global loads into registers (convert fp32 -> bf16) ----
        ushort8 av = {0, 0, 0, 0, 0, 0, 0, 0};
        if (arow_ok) {
            const int kk = k0 + akc;
            if (AMODE == A_PLAIN) {
                av = *(const ushort8*)(A + (size_t)arow_g * K + kk);
            } else if (AMODE == A_EDGE) {
                if (kk < 512) {
                    av = cvt8(mesh + (size_t)esrc[arow_g] * 512 + kk);
                } else if (kk < 1024) {
                    av = cvt8(gridf + (size_t)edst[arow_g] * 512 + (kk - 512));
                } else {
                    av = *(const ushort8*)(e0 + (size_t)arow_g * 512 + (kk - 1024));
                }
            } else { // A_NODE: [grid (fp32) | agg (fp32)]
                if (kk < 512) {
                    av = cvt8(gridf + (size_t)arow_g * 512 + kk);
                } else {
                    av = cvt8(aggIn + (size_t)arow_g * 512 + (kk - 512));
                }
            }
        }
        ushort8 bv = {0, 0, 0, 0, 0, 0, 0, 0};
        {
            const int ng = bn * 64 + bnc;
            if (nvec) {
                bv = cvt8(B + (size_t)(k0 + bkr) * N + ng);
            } else {
                #pragma unroll
                for (int j = 0; j < 8; ++j) {
                    int n = ng + j;
                    if (n < N) bv[j] = f2bf(B[(size_t)(k0 + bkr) * N + n]);
                }
            }
        }
        __syncthreads();   // previous compute done reading LDS
        *(ushort8*)(As + ar * 40 + akc) = av;
        {
            ushort4v lo, hi;
            #pragma unroll
            for (int j = 0; j < 4; ++j) { lo[j] = bv[j]; hi[j] = bv[j + 4]; }
            *(ushort4v*)(Bs + bkr * 68 + bnc)     = lo;
            *(ushort4v*)(Bs + bkr * 68 + bnc + 4) = hi;
        }
        __syncthreads();   // staging visible

        // ---- compute: 4 MFMA per wave per K-tile ----
        bf16x8 bfr;
        #pragma unroll
        for (int j = 0; j < 8; ++j)
            bfr[j] = (short)Bs[(quad * 8 + j) * 68 + w * 16 + ln];
        #pragma unroll
        for (int t = 0; t < 4; ++t) {
            bf16x8 af = *(const bf16x8*)(As + (t * 16 + ln) * 40 + quad * 8);
            acc[t] = __builtin_amdgcn_mfma_f32_16x16x32_bf16(af, bfr, acc[t], 0, 0, 0);
        }
    }

    // ---- epilogue ----
    const int col_g = bn * 64 + w * 16 + ln;
    const bool col_ok = (col_g < N);
    const float bcol = col_ok ? bias[col_g] : 0.f;
    #pragma unroll
    for (int t = 0; t < 4; ++t) {
        #pragma unroll
        for (int r = 0; r < 4; ++r) {
            const int row_g = bm * 64 + t * 16 + quad * 4 + r;
            if (row_g >= M || !col_ok) continue;
            float v = acc[t][r] + bcol;
            if (EPI == E_BIAS_BF16) {
                outB[(size_t)row_g * N + col_g] = f2bf(v);
            } else if (EPI == E_SILU_BF16) {
                outB[(size_t)row_g * N + col_g] = f2bf(silu_f(v));
            } else if (EPI == E_SCATTER) {
                v += bf2f(e0[(size_t)row_g * 512 + col_g]);   // residual e = e0 + mlp(..)
                atomicAdd(&aggOut[(size_t)edst[row_g] * 512 + col_g], v);
            } else if (EPI == E_RESID_BF16) {
                v += gridf[(size_t)row_g * 512 + col_g];
                outB[(size_t)row_g * N + col_g] = f2bf(v);
            } else { // E_OUT_F32 : final output, fp32
                outF[(size_t)row_g * N + col_g] = v;
            }
        }
    }
}

// h = silu(attrs @ emb_w0 + emb_b0), K=4 — one thread per output element.
__global__ __launch_bounds__(256)
void embed_l1(const float* __restrict__ attrs,
              const float* __restrict__ w0,
              const float* __restrict__ b0,
              unsigned short* __restrict__ h)
{
    const long long idx = (long long)blockIdx.x * 256 + threadIdx.x;
    if (idx >= (long long)NE * 512) return;
    const int row = (int)(idx >> 9);
    const int c = (int)(idx & 511);
    float acc = b0[c];
    #pragma unroll
    for (int k = 0; k < 4; ++k)
        acc += attrs[row * 4 + k] * w0[k * 512 + c];
    h[idx] = f2bf(silu_f(acc));
}

extern "C" void kernel_launch(void* const* d_in, const int* in_sizes, int n_in,
                              void* d_out, int out_size, void* d_ws, size_t ws_size,
                              hipStream_t stream)
{
    const float* mesh    = (const float*)d_in[0];
    const float* gridf   = (const float*)d_in[1];
    const float* attrs   = (const float*)d_in[2];
    const int*   esrc    = (const int*)d_in[3];
    const int*   edst    = (const int*)d_in[4];
    const float* emb_w0  = (const float*)d_in[5];
    const float* emb_b0  = (const float*)d_in[6];
    const float* emb_w1  = (const float*)d_in[7];
    const float* emb_b1  = (const float*)d_in[8];
    const float* edge_w0 = (const float*)d_in[9];
    const float* edge_b0 = (const float*)d_in[10];
    const float* edge_w1 = (const float*)d_in[11];
    const float* edge_b1 = (const float*)d_in[12];
    const float* node_w0 = (const float*)d_in[13];
    const float* node_b0 = (const float*)d_in[14];
    const float* node_w1 = (const float*)d_in[15];
    const float* node_b1 = (const float*)d_in[16];
    const float* out_w0  = (const float*)d_in[17];
    const float* out_b0  = (const float*)d_in[18];
    const float* out_w1  = (const float*)d_in[19];
    const float* out_b1  = (const float*)d_in[20];

    // ws layout: e0 (NE*512 bf16) | hb (NE*512 bf16) | agg (NG*512 f32) = 534 MB
    char* ws = (char*)d_ws;
    unsigned short* e0 = (unsigned short*)ws;
    unsigned short* hb = (unsigned short*)(ws + (size_t)NE * 512 * 2);
    float*          agg = (float*)(ws + (size_t)2 * NE * 512 * 2);
    unsigned short* g2 = e0;   // reuse e0 region for grid2 (e0 dead after G4)

    hipMemsetAsync(agg, 0, (size_t)NG * 512 * sizeof(float), stream);

    dim3 blk(256);
    // L1: hb = silu(attrs @ emb_w0 + b)
    embed_l1<<<(int)(((long long)NE * 512 + 255) / 256), blk, 0, stream>>>(attrs, emb_w0, emb_b0, hb);
    // G2: e0 = hb @ emb_w1 + b
    {
        dim3 g((NE + 63) / 64, 8);
        gemm64<A_PLAIN, E_BIAS_BF16><<<g, blk, 0, stream>>>(hb, emb_w1, emb_b1, NE, 512, 512,
            nullptr, nullptr, nullptr, nullptr, nullptr, nullptr, nullptr, e0, nullptr);
    }
    // G3: hb = silu([mesh[src] | grid[dst] | e0] @ edge_w0 + b)
    {
        dim3 g((NE + 63) / 64, 8);
        gemm64<A_EDGE, E_SILU_BF16><<<g, blk, 0, stream>>>(nullptr, edge_w0, edge_b0, NE, 512, 1536,
            mesh, gridf, e0, esrc, edst, nullptr, nullptr, hb, nullptr);
    }
    // G4: agg[dst[r]] += e0[r] + hb @ edge_w1 + b   (fused segment_sum)
    {
        dim3 g((NE + 63) / 64, 8);
        gemm64<A_PLAIN, E_SCATTER><<<g, blk, 0, stream>>>(hb, edge_w1, edge_b1, NE, 512, 512,
            nullptr, nullptr, e0, nullptr, edst, nullptr, agg, nullptr, nullptr);
    }
    // G5: hb = silu([grid | agg] @ node_w0 + b)
    {
        dim3 g((NG + 63) / 64, 8);
        gemm64<A_NODE, E_SILU_BF16><<<g, blk, 0, stream>>>(nullptr, node_w0, node_b0, NG, 512, 1024,
            nullptr, gridf, nullptr, nullptr, nullptr, agg, nullptr, hb, nullptr);
    }
    // G6: g2 = grid + hb @ node_w1 + b
    {
        dim3 g((NG + 63) / 64, 8);
        gemm64<A_PLAIN, E_RESID_BF16><<<g, blk, 0, stream>>>(hb, node_w1, node_b1, NG, 512, 512,
            nullptr, gridf, nullptr, nullptr, nullptr, nullptr, nullptr, g2, nullptr);
    }
    // G7: hb = silu(g2 @ out_w0 + b)
    {
        dim3 g((NG + 63) / 64, 8);
        gemm64<A_PLAIN, E_SILU_BF16><<<g, blk, 0, stream>>>(g2, out_w0, out_b0, NG, 512, 512,
            nullptr, nullptr, nullptr, nullptr, nullptr, nullptr, nullptr, hb, nullptr);
    }
    // G8: out = hb @ out_w1 + b  (fp32 store, N=471)
    {
        dim3 g((NG + 63) / 64, (NOUT + 63) / 64);
        gemm64<A_PLAIN, E_OUT_F32><<<g, blk, 0, stream>>>(hb, out_w1, out_b1, NG, NOUT, 512,
            nullptr, nullptr, nullptr, nullptr, nullptr, nullptr, nullptr, nullptr, (float*)d_out);
    }
}